// Round 7
// baseline (2099.631 us; speedup 1.0000x reference)
//
#include <hip/hip_runtime.h>

#define TT 50
#define BB 512
#define II 784
#define HH 800
#define OO 10
#define BH (BB*HH)   // 409600
#define MM (TT*BB)   // 25600

// ---------------------------------------------------------------------------
// K1: x1d[m][n] = sum_k x[m][k]*W1[n][k] + b1[n], all f64 (order-free: proven
// R1/R3/R5/R6). M=25600 N=800 K=784. Tile 128m x 80n, KC=8 double-buffered,
// frag 8m contiguous x 5n strided-16. Grid (10 n, 200 m): n varies fastest so
// blocks sharing an x-tile dispatch together (x streamed ~once).
// LDS 27,136 B total. A-frag reads = double2 (16B), conflict-free/2-way.
// ---------------------------------------------------------------------------
__global__ __launch_bounds__(256) void k_gemm1(
    const float* __restrict__ x, const float* __restrict__ W1,
    const float* __restrict__ b1, double* __restrict__ x1d)
{
    __shared__ double As[2][8*130];
    __shared__ double Bs[2][8*82];
    const int n0 = blockIdx.x * 80;
    const int m0 = blockIdx.y * 128;
    const int tid = threadIdx.x;
    const int tx = tid & 15, ty = tid >> 4;
    double acc[8][5] = {};

    const int ar = tid >> 1;            // 0..127  A row
    const int ak = (tid & 1) * 4;       // 0 or 4  A k-offset
    const float* aptr = x + (long)(m0 + ar) * II + ak;
    const int br = tid >> 1;            // 0..79 (tid<160)  B row
    const int bk = (tid & 1) * 4;
    const float* bptr = W1 + (long)(n0 + br) * II + bk;
    const bool bact = tid < 160;

    float4 afr = *(const float4*)(aptr);
    float4 bfr = bact ? *(const float4*)(bptr) : make_float4(0.f,0.f,0.f,0.f);

#define STAGE1(BUF) do {                                                    \
        As[BUF][(ak+0)*130+ar] = (double)afr.x;                             \
        As[BUF][(ak+1)*130+ar] = (double)afr.y;                             \
        As[BUF][(ak+2)*130+ar] = (double)afr.z;                             \
        As[BUF][(ak+3)*130+ar] = (double)afr.w;                             \
        if (bact) {                                                         \
            Bs[BUF][(bk+0)*82+br] = (double)bfr.x;                          \
            Bs[BUF][(bk+1)*82+br] = (double)bfr.y;                          \
            Bs[BUF][(bk+2)*82+br] = (double)bfr.z;                          \
            Bs[BUF][(bk+3)*82+br] = (double)bfr.w;                          \
        }                                                                   \
    } while (0)

    STAGE1(0);
    __syncthreads();
    for (int c = 0; c < 98; ++c) {      // 784 = 98*8
        const int cur = c & 1;
        if (c < 97) {
            afr = *(const float4*)(aptr + (c+1)*8);
            if (bact) bfr = *(const float4*)(bptr + (c+1)*8);
        }
        #pragma unroll
        for (int k = 0; k < 8; ++k) {
            const double2* Ap = (const double2*)&As[cur][k*130 + ty*8];
            const double2 a01 = Ap[0], a23 = Ap[1], a45 = Ap[2], a67 = Ap[3];
            double bv[5];
            #pragma unroll
            for (int j = 0; j < 5; ++j) bv[j] = Bs[cur][k*82 + tx + 16*j];
            const double am[8] = {a01.x, a01.y, a23.x, a23.y,
                                  a45.x, a45.y, a67.x, a67.y};
            #pragma unroll
            for (int i = 0; i < 8; ++i)
                #pragma unroll
                for (int j = 0; j < 5; ++j)
                    acc[i][j] = fma(am[i], bv[j], acc[i][j]);
        }
        if (c < 97) STAGE1(cur ^ 1);
        __syncthreads();
    }
    double bb[5];
    #pragma unroll
    for (int j = 0; j < 5; ++j) bb[j] = (double)b1[n0 + tx + 16*j];
    #pragma unroll
    for (int i = 0; i < 8; ++i) {
        const long m = m0 + ty*8 + i;
        #pragma unroll
        for (int j = 0; j < 5; ++j)
            x1d[m*HH + n0 + tx + 16*j] = acc[i][j] + bb[j];
    }
#undef STAGE1
}

// ---------------------------------------------------------------------------
// K2: LIF scan layer 1, f64 (PROVEN, unchanged). Writes u8 spikes (ws) +
// s1r f32 (d_out, write-only).
// ---------------------------------------------------------------------------
__global__ __launch_bounds__(256) void k_mem1(
    const double* __restrict__ x1d, const float* __restrict__ thresh1,
    unsigned char* __restrict__ s1c, float* __restrict__ s1r)
{
    const int lid = blockIdx.x*256 + threadIdx.x;   // = b*HH + h
    const int h = lid % HH;
    const double th = (double)thresh1[h];
    double mem = 0.0;
    for (int t = 0; t < TT; ++t) {
        const long idx = (long)t*BH + lid;
        mem = 0.95*mem + x1d[idx];
        const bool spk = mem > th;
        s1c[idx] = spk ? 1 : 0;
        s1r[idx] = spk ? 1.0f : 0.0f;
        if (spk) mem = 0.0;
    }
}

// ---------------------------------------------------------------------------
// K3: z2[m][n] = chain_k( s1[m][k]*W2[n][k] ) — strict ascending-k single
// __fmaf_rn chain per output (EXACT R5/R6 semantics; scheduling-only changes).
// Tile 128m x 80n, KC=16 double-buffered, frag 8m contig x (4n contig + 1).
// Explicit float4 LDS reads/stores; register prefetch; grid (10 n, 200 m).
// ---------------------------------------------------------------------------
__global__ __launch_bounds__(256) void k_gemm2(
    const unsigned char* __restrict__ s1c, const float* __restrict__ W2,
    float* __restrict__ z2)
{
    __shared__ float As[2][16*132];
    __shared__ float Bs[2][16*84];
    const int n0 = blockIdx.x * 80;
    const int m0 = blockIdx.y * 128;
    const int tid = threadIdx.x;
    const int tx = tid & 15, ty = tid >> 4;
    float acc[8][5] = {};

    const int ar = tid >> 1;             // 0..127
    const int ak = (tid & 1) * 8;        // 0 or 8
    const unsigned char* aptr = s1c + (long)(m0 + ar)*HH + ak;
    const int b0r = tid >> 2,        b0k = (tid & 3) * 4;
    const int q1 = tid + 256;
    const int b1r = q1 >> 2,         b1k = (q1 & 3) * 4;
    const float* bptr0 = W2 + (long)(n0 + b0r)*HH + b0k;
    const float* bptr1 = W2 + (long)(n0 + b1r)*HH + b1k;
    const bool bact = tid < 64;

    uint2 au = *(const uint2*)(aptr);
    float4 bf0 = *(const float4*)(bptr0);
    float4 bf1 = bact ? *(const float4*)(bptr1) : make_float4(0.f,0.f,0.f,0.f);

#define STAGE2(BUF) do {                                                    \
        const unsigned int d0 = au.x, d1 = au.y;                            \
        As[BUF][(ak+0)*132+ar] = (float)( d0        & 0xffu);               \
        As[BUF][(ak+1)*132+ar] = (float)((d0 >>  8) & 0xffu);               \
        As[BUF][(ak+2)*132+ar] = (float)((d0 >> 16) & 0xffu);               \
        As[BUF][(ak+3)*132+ar] = (float)((d0 >> 24) & 0xffu);               \
        As[BUF][(ak+4)*132+ar] = (float)( d1        & 0xffu);               \
        As[BUF][(ak+5)*132+ar] = (float)((d1 >>  8) & 0xffu);               \
        As[BUF][(ak+6)*132+ar] = (float)((d1 >> 16) & 0xffu);               \
        As[BUF][(ak+7)*132+ar] = (float)((d1 >> 24) & 0xffu);               \
        Bs[BUF][(b0k+0)*84+b0r] = bf0.x;                                    \
        Bs[BUF][(b0k+1)*84+b0r] = bf0.y;                                    \
        Bs[BUF][(b0k+2)*84+b0r] = bf0.z;                                    \
        Bs[BUF][(b0k+3)*84+b0r] = bf0.w;                                    \
        if (bact) {                                                         \
            Bs[BUF][(b1k+0)*84+b1r] = bf1.x;                                \
            Bs[BUF][(b1k+1)*84+b1r] = bf1.y;                                \
            Bs[BUF][(b1k+2)*84+b1r] = bf1.z;                                \
            Bs[BUF][(b1k+3)*84+b1r] = bf1.w;                                \
        }                                                                   \
    } while (0)

    STAGE2(0);
    __syncthreads();
    for (int c = 0; c < 50; ++c) {      // 800 = 50*16
        const int cur = c & 1;
        if (c < 49) {
            au = *(const uint2*)(aptr + (c+1)*16);
            bf0 = *(const float4*)(bptr0 + (c+1)*16);
            if (bact) bf1 = *(const float4*)(bptr1 + (c+1)*16);
        }
        #pragma unroll
        for (int k = 0; k < 16; ++k) {
            const float4 A0 = *(const float4*)&As[cur][k*132 + ty*8];
            const float4 A1 = *(const float4*)&As[cur][k*132 + ty*8 + 4];
            const float4 Bv = *(const float4*)&Bs[cur][k*84 + tx*4];
            const float  b4 = Bs[cur][k*84 + 64 + tx];
            const float am[8] = {A0.x, A0.y, A0.z, A0.w, A1.x, A1.y, A1.z, A1.w};
            const float bv[5] = {Bv.x, Bv.y, Bv.z, Bv.w, b4};
            #pragma unroll
            for (int i = 0; i < 8; ++i)
                #pragma unroll
                for (int j = 0; j < 5; ++j)
                    acc[i][j] = __fmaf_rn(am[i], bv[j], acc[i][j]);
        }
        if (c < 49) STAGE2(cur ^ 1);
        __syncthreads();
    }
    #pragma unroll
    for (int i = 0; i < 8; ++i) {
        const long m = m0 + ty*8 + i;
        *(float4*)&z2[m*HH + n0 + tx*4] =
            make_float4(acc[i][0], acc[i][1], acc[i][2], acc[i][3]);
        z2[m*HH + n0 + 64 + tx] = acc[i][4];
    }
#undef STAGE2
}

// ---------------------------------------------------------------------------
// K4: layer-2 membrane scan, strict fp32 np order (PROVEN, unchanged).
// ---------------------------------------------------------------------------
__global__ __launch_bounds__(256) void k_scan2(
    const float* __restrict__ z2, const float* __restrict__ b2,
    const float* __restrict__ thresh2, float* __restrict__ s2r,
    unsigned char* __restrict__ s2c)
{
    const int lid = blockIdx.x*256 + threadIdx.x;   // = b*HH + n
    const int n = lid % HH;
    const float b2v = b2[n];
    const float thv = thresh2[n];
    float m = 0.0f;
    for (int t = 0; t < TT; ++t) {
        const long idx = (long)t*BH + lid;
        const float m2 = __fadd_rn(
            __fadd_rn(__fmul_rn(0.95f, m), z2[idx]), b2v);
        const bool spk = m2 > thv;
        s2r[idx] = spk ? 1.0f : 0.0f;
        s2c[idx] = spk ? 1 : 0;
        m = spk ? 0.0f : m2;
    }
}

// ---------------------------------------------------------------------------
// K5: z3[m][o] = strict ascending-k chain (PROVEN, unchanged).
// ---------------------------------------------------------------------------
__global__ __launch_bounds__(256) void k_gemm3(
    const unsigned char* __restrict__ s2c, const float* __restrict__ W3,
    float* __restrict__ z3)
{
    const long m = blockIdx.x*256 + threadIdx.x;
    const unsigned char* row = s2c + m*HH;
    float acc[10] = {};
    for (int k0 = 0; k0 < HH; k0 += 16) {
        const uint4 v = *(const uint4*)(row + k0);
        const unsigned int d[4] = {v.x, v.y, v.z, v.w};
        #pragma unroll
        for (int w = 0; w < 4; ++w) {
            #pragma unroll
            for (int j = 0; j < 4; ++j) {
                const float sv = (float)((d[w] >> (8*j)) & 0xffu);
                const int k = k0 + w*4 + j;
                #pragma unroll
                for (int o = 0; o < 10; ++o)
                    acc[o] = __fmaf_rn(sv, W3[o*HH + k], acc[o]);
            }
        }
    }
    #pragma unroll
    for (int o = 0; o < 10; ++o)
        z3[m*OO + o] = acc[o];
}

// ---------------------------------------------------------------------------
// K6: layer-3 membrane scan, strict fp32 (PROVEN, unchanged).
// ---------------------------------------------------------------------------
__global__ __launch_bounds__(256) void k_scan3(
    const float* __restrict__ z3, const float* __restrict__ b3,
    float* __restrict__ s3r, float* __restrict__ out0)
{
    const int gid = blockIdx.x*256 + threadIdx.x;   // = b*OO + o
    if (gid >= BB*OO) return;
    const int o = gid % OO;
    const float b3v = b3[o];
    float mem = 0.0f, cnt = 0.0f;
    for (int t = 0; t < TT; ++t) {
        const float m3 = __fadd_rn(
            __fadd_rn(__fmul_rn(0.95f, mem), z3[(long)t*BB*OO + gid]), b3v);
        const bool spk = m3 > 1.0f;
        s3r[(long)t*BB*OO + gid] = spk ? 1.0f : 0.0f;
        if (spk) cnt = __fadd_rn(cnt, 1.0f);
        mem = spk ? 0.0f : m3;
    }
    out0[gid] = cnt;
}

// ---------------------------------------------------------------------------
extern "C" void kernel_launch(void* const* d_in, const int* in_sizes, int n_in,
                              void* d_out, int out_size, void* d_ws, size_t ws_size,
                              hipStream_t stream)
{
    const float* x   = (const float*)d_in[0];
    const float* W1  = (const float*)d_in[1];
    const float* b1  = (const float*)d_in[2];
    const float* W2  = (const float*)d_in[3];
    const float* b2  = (const float*)d_in[4];
    const float* W3  = (const float*)d_in[5];
    const float* b3  = (const float*)d_in[6];
    const float* th1 = (const float*)d_in[7];
    const float* th2 = (const float*)d_in[8];

    float* out0 = (float*)d_out;                    // (B, OUT)   d_out is
    float* s1r  = out0 + BB*OO;                     // (T, B, H)  WRITE-ONLY
    float* s2r  = s1r + (long)TT*BH;                // (T, B, H)
    float* s3r  = s2r + (long)TT*BH;                // (T, B, OUT)

    // ws layout (204.8 MB, proven budget):
    //   [0 .. 163.84 MB)   x1d f64 — dead after k_mem1; region reused for
    //        z2 f32 [0 .. 81.92 MB) and z3 f32 [84 MB .. 85.03 MB)
    //   [163.84 .. 184.32 MB) s1c u8
    //   [184.32 .. 204.80 MB) s2c u8
    char* p = (char*)d_ws;
    double* x1d = (double*)p;
    float*  z2  = (float*)p;
    float*  z3  = (float*)(p + 84000000);
    unsigned char* s1c = (unsigned char*)(p + 163840000);
    unsigned char* s2c = s1c + (size_t)TT*BH;
    (void)ws_size;

    k_gemm1<<<dim3(10,200), dim3(256), 0, stream>>>(x, W1, b1, x1d);
    k_mem1 <<<dim3(1600),   dim3(256), 0, stream>>>(x1d, th1, s1c, s1r);
    k_gemm2<<<dim3(10,200), dim3(256), 0, stream>>>(s1c, W2, z2);
    k_scan2<<<dim3(1600),   dim3(256), 0, stream>>>(z2, b2, th2, s2r, s2c);
    k_gemm3<<<dim3(100),    dim3(256), 0, stream>>>(s2c, W3, z3);
    k_scan3<<<dim3(20),     dim3(256), 0, stream>>>(z3, b3, s3r, out0);
}

// Round 8
// 1501.486 us; speedup vs baseline: 1.3984x; 1.3984x over previous
//
#include <hip/hip_runtime.h>

#define TT 50
#define BB 512
#define II 784
#define HH 800
#define OO 10
#define BH (BB*HH)   // 409600
#define MM (TT*BB)   // 25600

// ---------------------------------------------------------------------------
// K1: x1d[m][n] = sum_k x[m][k]*W1[n][k] + b1[n], all f64 (order-free, proven).
// R8: occupancy-first design. Tile 64m x 80n, acc 4x5 (40 VGPR), KC=16
// single-buffered, no register prefetch (R7 lesson: prefetch VGPRs killed
// occupancy 30%->12%). LDS 18.9 KB -> ~5-6 blocks/CU. A-frags contiguous
// (double2 reads); B-frags strided-16 scalar. Grid (400 m, 10 n) m-fastest.
// ---------------------------------------------------------------------------
__global__ __launch_bounds__(256) void k_gemm1(
    const float* __restrict__ x, const float* __restrict__ W1,
    const float* __restrict__ b1, double* __restrict__ x1d)
{
    __shared__ double As[16*66];   // [k][m], pad 66
    __shared__ double Bs[16*82];   // [k][n], pad 82
    const int m0 = blockIdx.x * 64;
    const int n0 = blockIdx.y * 80;
    const int tid = threadIdx.x;
    const int tx = tid & 15, ty = tid >> 4;
    double acc[4][5] = {};

    // A staging: 64 rows x 16 k = 256 float4 tasks (one per thread)
    const int ar = tid >> 2;          // 0..63
    const int ak = (tid & 3) * 4;     // 0,4,8,12
    const float* aptr = x + (long)(m0 + ar)*II + ak;
    // B staging: 80 rows x 16 k = 320 float4 tasks (tid, tid+256 for tid<64)
    const int b0r = tid >> 2,  b0k = (tid & 3) * 4;
    const int q1  = tid + 256;
    const int b1r = q1 >> 2,   b1k = (q1 & 3) * 4;
    const float* bptr0 = W1 + (long)(n0 + b0r)*II + b0k;
    const float* bptr1 = W1 + (long)(n0 + b1r)*II + b1k;
    const bool bact = tid < 64;

    for (int k0 = 0; k0 < II; k0 += 16) {   // 784 = 49*16
        const float4 av  = *(const float4*)(aptr + k0);
        const float4 bv0 = *(const float4*)(bptr0 + k0);
        float4 bv1;
        if (bact) bv1 = *(const float4*)(bptr1 + k0);
        __syncthreads();   // protect previous chunk's reads
        As[(ak+0)*66 + ar] = (double)av.x;
        As[(ak+1)*66 + ar] = (double)av.y;
        As[(ak+2)*66 + ar] = (double)av.z;
        As[(ak+3)*66 + ar] = (double)av.w;
        Bs[(b0k+0)*82 + b0r] = (double)bv0.x;
        Bs[(b0k+1)*82 + b0r] = (double)bv0.y;
        Bs[(b0k+2)*82 + b0r] = (double)bv0.z;
        Bs[(b0k+3)*82 + b0r] = (double)bv0.w;
        if (bact) {
            Bs[(b1k+0)*82 + b1r] = (double)bv1.x;
            Bs[(b1k+1)*82 + b1r] = (double)bv1.y;
            Bs[(b1k+2)*82 + b1r] = (double)bv1.z;
            Bs[(b1k+3)*82 + b1r] = (double)bv1.w;
        }
        __syncthreads();
        #pragma unroll
        for (int k = 0; k < 16; ++k) {
            const double2* Ap = (const double2*)&As[k*66 + ty*4];
            const double2 a01 = Ap[0], a23 = Ap[1];
            const double am[4] = {a01.x, a01.y, a23.x, a23.y};
            double bv[5];
            #pragma unroll
            for (int j = 0; j < 5; ++j) bv[j] = Bs[k*82 + tx + 16*j];
            #pragma unroll
            for (int i = 0; i < 4; ++i)
                #pragma unroll
                for (int j = 0; j < 5; ++j)
                    acc[i][j] = fma(am[i], bv[j], acc[i][j]);
        }
    }
    double bb[5];
    #pragma unroll
    for (int j = 0; j < 5; ++j) bb[j] = (double)b1[n0 + tx + 16*j];
    #pragma unroll
    for (int i = 0; i < 4; ++i) {
        const long m = m0 + ty*4 + i;
        #pragma unroll
        for (int j = 0; j < 5; ++j)
            x1d[m*HH + n0 + tx + 16*j] = acc[i][j] + bb[j];
    }
}

// ---------------------------------------------------------------------------
// K2: LIF scan layer 1, f64 (PROVEN, unchanged).
// ---------------------------------------------------------------------------
__global__ __launch_bounds__(256) void k_mem1(
    const double* __restrict__ x1d, const float* __restrict__ thresh1,
    unsigned char* __restrict__ s1c, float* __restrict__ s1r)
{
    const int lid = blockIdx.x*256 + threadIdx.x;   // = b*HH + h
    const int h = lid % HH;
    const double th = (double)thresh1[h];
    double mem = 0.0;
    for (int t = 0; t < TT; ++t) {
        const long idx = (long)t*BH + lid;
        mem = 0.95*mem + x1d[idx];
        const bool spk = mem > th;
        s1c[idx] = spk ? 1 : 0;
        s1r[idx] = spk ? 1.0f : 0.0f;
        if (spk) mem = 0.0;
    }
}

// ---------------------------------------------------------------------------
// K3: z2 = s1 @ W2.T — strict ascending-k single __fmaf_rn chain per output.
// EXACT R6 version (proven fast + bit-exact). Tile 128m x 80n, KC=32,
// single-buffered, grid (200 m, 10 n) m-fastest.
// ---------------------------------------------------------------------------
__global__ __launch_bounds__(256) void k_gemm2(
    const unsigned char* __restrict__ s1c, const float* __restrict__ W2,
    float* __restrict__ z2)
{
    __shared__ float As[32*132];
    __shared__ float Bs[32*84];
    const int m0 = blockIdx.x * 128;
    const int n0 = blockIdx.y * 80;
    const int tid = threadIdx.x;
    const int tx = tid & 15, ty = tid >> 4;
    float acc[8][5] = {};

    const int sm = tid >> 1;          // 0..127
    const int sk = (tid & 1) * 16;    // 0 or 16
    const int b0n = tid >> 3,        b0k = (tid & 7) * 4;
    const int q1 = tid + 256, b1n = q1 >> 3, b1k = (q1 & 7) * 4;
    const int q2 = tid + 512, b2n = q2 >> 3, b2k = (q2 & 7) * 4;

    for (int k0 = 0; k0 < HH; k0 += 32) {   // 800 = 25*32
        const uint4 av = *(const uint4*)(s1c + (long)(m0+sm)*HH + k0 + sk);
        const float4 w0 = *(const float4*)(W2 + (long)(n0+b0n)*HH + k0 + b0k);
        const float4 w1 = *(const float4*)(W2 + (long)(n0+b1n)*HH + k0 + b1k);
        float4 w2;
        if (tid < 128)
            w2 = *(const float4*)(W2 + (long)(n0+b2n)*HH + k0 + b2k);
        __syncthreads();
        {
            const unsigned int d[4] = {av.x, av.y, av.z, av.w};
            #pragma unroll
            for (int w = 0; w < 4; ++w) {
                #pragma unroll
                for (int j = 0; j < 4; ++j)
                    As[(sk + w*4 + j)*132 + sm] =
                        (float)((d[w] >> (8*j)) & 0xffu);
            }
        }
        Bs[(b0k+0)*84+b0n] = w0.x; Bs[(b0k+1)*84+b0n] = w0.y;
        Bs[(b0k+2)*84+b0n] = w0.z; Bs[(b0k+3)*84+b0n] = w0.w;
        Bs[(b1k+0)*84+b1n] = w1.x; Bs[(b1k+1)*84+b1n] = w1.y;
        Bs[(b1k+2)*84+b1n] = w1.z; Bs[(b1k+3)*84+b1n] = w1.w;
        if (tid < 128) {
            Bs[(b2k+0)*84+b2n] = w2.x; Bs[(b2k+1)*84+b2n] = w2.y;
            Bs[(b2k+2)*84+b2n] = w2.z; Bs[(b2k+3)*84+b2n] = w2.w;
        }
        __syncthreads();
        #pragma unroll
        for (int k = 0; k < 32; ++k) {
            float a[8], b[5];
            #pragma unroll
            for (int i = 0; i < 8; ++i) a[i] = As[k*132 + ty*8 + i];
            #pragma unroll
            for (int j = 0; j < 4; ++j) b[j] = Bs[k*84 + tx*4 + j];
            b[4] = Bs[k*84 + 64 + tx];
            #pragma unroll
            for (int i = 0; i < 8; ++i)
                #pragma unroll
                for (int j = 0; j < 5; ++j)
                    acc[i][j] = __fmaf_rn(a[i], b[j], acc[i][j]);
        }
        __syncthreads();
    }
    #pragma unroll
    for (int i = 0; i < 8; ++i) {
        const long m = m0 + ty*8 + i;
        #pragma unroll
        for (int j = 0; j < 4; ++j)
            z2[m*HH + n0 + tx*4 + j] = acc[i][j];
        z2[m*HH + n0 + 64 + tx] = acc[i][4];
    }
}

// ---------------------------------------------------------------------------
// K4: layer-2 membrane scan, strict fp32 np order (PROVEN, unchanged).
// ---------------------------------------------------------------------------
__global__ __launch_bounds__(256) void k_scan2(
    const float* __restrict__ z2, const float* __restrict__ b2,
    const float* __restrict__ thresh2, float* __restrict__ s2r,
    unsigned char* __restrict__ s2c)
{
    const int lid = blockIdx.x*256 + threadIdx.x;   // = b*HH + n
    const int n = lid % HH;
    const float b2v = b2[n];
    const float thv = thresh2[n];
    float m = 0.0f;
    for (int t = 0; t < TT; ++t) {
        const long idx = (long)t*BH + lid;
        const float m2 = __fadd_rn(
            __fadd_rn(__fmul_rn(0.95f, m), z2[idx]), b2v);
        const bool spk = m2 > thv;
        s2r[idx] = spk ? 1.0f : 0.0f;
        s2c[idx] = spk ? 1 : 0;
        m = spk ? 0.0f : m2;
    }
}

// ---------------------------------------------------------------------------
// K5: z3[m][o] = strict ascending-k chain (PROVEN, unchanged).
// ---------------------------------------------------------------------------
__global__ __launch_bounds__(256) void k_gemm3(
    const unsigned char* __restrict__ s2c, const float* __restrict__ W3,
    float* __restrict__ z3)
{
    const long m = blockIdx.x*256 + threadIdx.x;
    const unsigned char* row = s2c + m*HH;
    float acc[10] = {};
    for (int k0 = 0; k0 < HH; k0 += 16) {
        const uint4 v = *(const uint4*)(row + k0);
        const unsigned int d[4] = {v.x, v.y, v.z, v.w};
        #pragma unroll
        for (int w = 0; w < 4; ++w) {
            #pragma unroll
            for (int j = 0; j < 4; ++j) {
                const float sv = (float)((d[w] >> (8*j)) & 0xffu);
                const int k = k0 + w*4 + j;
                #pragma unroll
                for (int o = 0; o < 10; ++o)
                    acc[o] = __fmaf_rn(sv, W3[o*HH + k], acc[o]);
            }
        }
    }
    #pragma unroll
    for (int o = 0; o < 10; ++o)
        z3[m*OO + o] = acc[o];
}

// ---------------------------------------------------------------------------
// K6: layer-3 membrane scan, strict fp32 (PROVEN, unchanged).
// ---------------------------------------------------------------------------
__global__ __launch_bounds__(256) void k_scan3(
    const float* __restrict__ z3, const float* __restrict__ b3,
    float* __restrict__ s3r, float* __restrict__ out0)
{
    const int gid = blockIdx.x*256 + threadIdx.x;   // = b*OO + o
    if (gid >= BB*OO) return;
    const int o = gid % OO;
    const float b3v = b3[o];
    float mem = 0.0f, cnt = 0.0f;
    for (int t = 0; t < TT; ++t) {
        const float m3 = __fadd_rn(
            __fadd_rn(__fmul_rn(0.95f, mem), z3[(long)t*BB*OO + gid]), b3v);
        const bool spk = m3 > 1.0f;
        s3r[(long)t*BB*OO + gid] = spk ? 1.0f : 0.0f;
        if (spk) cnt = __fadd_rn(cnt, 1.0f);
        mem = spk ? 0.0f : m3;
    }
    out0[gid] = cnt;
}

// ---------------------------------------------------------------------------
extern "C" void kernel_launch(void* const* d_in, const int* in_sizes, int n_in,
                              void* d_out, int out_size, void* d_ws, size_t ws_size,
                              hipStream_t stream)
{
    const float* x   = (const float*)d_in[0];
    const float* W1  = (const float*)d_in[1];
    const float* b1  = (const float*)d_in[2];
    const float* W2  = (const float*)d_in[3];
    const float* b2  = (const float*)d_in[4];
    const float* W3  = (const float*)d_in[5];
    const float* b3  = (const float*)d_in[6];
    const float* th1 = (const float*)d_in[7];
    const float* th2 = (const float*)d_in[8];

    float* out0 = (float*)d_out;                    // (B, OUT)   d_out is
    float* s1r  = out0 + BB*OO;                     // (T, B, H)  WRITE-ONLY
    float* s2r  = s1r + (long)TT*BH;                // (T, B, H)
    float* s3r  = s2r + (long)TT*BH;                // (T, B, OUT)

    // ws layout (204.8 MB, proven budget):
    //   [0 .. 163.84 MB)   x1d f64 — dead after k_mem1; region reused for
    //        z2 f32 [0 .. 81.92 MB) and z3 f32 [84 MB .. 85.03 MB)
    //   [163.84 .. 184.32 MB) s1c u8
    //   [184.32 .. 204.80 MB) s2c u8
    char* p = (char*)d_ws;
    double* x1d = (double*)p;
    float*  z2  = (float*)p;
    float*  z3  = (float*)(p + 84000000);
    unsigned char* s1c = (unsigned char*)(p + 163840000);
    unsigned char* s2c = s1c + (size_t)TT*BH;
    (void)ws_size;

    k_gemm1<<<dim3(400,10), dim3(256), 0, stream>>>(x, W1, b1, x1d);
    k_mem1 <<<dim3(1600),   dim3(256), 0, stream>>>(x1d, th1, s1c, s1r);
    k_gemm2<<<dim3(200,10), dim3(256), 0, stream>>>(s1c, W2, z2);
    k_scan2<<<dim3(1600),   dim3(256), 0, stream>>>(z2, b2, th2, s2r, s2c);
    k_gemm3<<<dim3(100),    dim3(256), 0, stream>>>(s2c, W3, z3);
    k_scan3<<<dim3(20),     dim3(256), 0, stream>>>(z3, b3, s3r, out0);
}